// Round 4
// baseline (349.035 us; speedup 1.0000x reference)
//
#include <hip/hip_runtime.h>
#include <math.h>

#define BB 2
#define LL 2048
#define DD 512
#define HH 8
#define DK 64
#define SK 40   // sample_k
#define UU 40   // top-k u
#define BH (BB*HH)   // 16
#define KT 1536      // split-bf16 packed K = 3*512

typedef __attribute__((ext_vector_type(8))) __bf16 bf16x8;
typedef __attribute__((ext_vector_type(4))) float f32x4;

__device__ inline ushort f2bf_rn(float f) {
    unsigned u = __float_as_uint(f);
    unsigned r = (u + 0x7fffu + ((u >> 16) & 1u)) >> 16;
    return (ushort)r;
}
__device__ inline float bf2f(ushort h) { return __uint_as_float(((unsigned)h) << 16); }

// ---------------- fill attns with 1/L ----------------
__global__ __launch_bounds__(256) void fill_attns(float* __restrict__ attns, long n4) {
    const float c = 1.0f / (float)LL;
    const float4 val = make_float4(c, c, c, c);
    float4* p = (float4*)attns;
    long stride = (long)gridDim.x * blockDim.x;
    for (long i = (long)blockIdx.x * blockDim.x + threadIdx.x; i < n4; i += stride)
        p[i] = val;
}

// ---------------- pack x->A2 [4096][1536]=[xh|xh|xl], W->B2 [p][512][1536]=[Wh|Wl|Wh] ----------------
__global__ __launch_bounds__(256) void pack_all(
    const float* __restrict__ x,
    const float* __restrict__ Wq, const float* __restrict__ Wk, const float* __restrict__ Wv,
    ushort* __restrict__ A2, ushort* __restrict__ B2)
{
    const int bid = blockIdx.x;
    const float* src; ushort* dstrow; int r, c;
    bool isW = (bid >= 1024);
    if (!isW) {
        const int g = bid * 256 + threadIdx.x;       // 0..262143
        r = g >> 6; c = (g & 63) * 8;
        src = x + (long)r * DD + c;
        dstrow = A2 + (long)r * KT;
    } else {
        const int wb = bid - 1024;
        const int p = wb >> 7;
        const float* W = (p == 0) ? Wq : ((p == 1) ? Wk : Wv);
        const int rem = (wb & 127) * 256 + threadIdx.x;  // 0..32767
        r = rem >> 6; c = (rem & 63) * 8;
        src = W + (long)r * DD + c;
        dstrow = B2 + ((long)p * DD + r) * KT;
    }
    const float4 f0 = *(const float4*)&src[0];
    const float4 f1 = *(const float4*)&src[4];
    float f[8] = {f0.x, f0.y, f0.z, f0.w, f1.x, f1.y, f1.z, f1.w};
    union { ushort s[8]; uint4 u; } H, L;
    #pragma unroll
    for (int i = 0; i < 8; ++i) {
        H.s[i] = f2bf_rn(f[i]);
        L.s[i] = f2bf_rn(f[i] - bf2f(H.s[i]));
    }
    if (!isW) {
        *(uint4*)(dstrow + c)        = H.u;
        *(uint4*)(dstrow + 512 + c)  = H.u;
        *(uint4*)(dstrow + 1024 + c) = L.u;
    } else {
        *(uint4*)(dstrow + c)        = H.u;
        *(uint4*)(dstrow + 512 + c)  = L.u;
        *(uint4*)(dstrow + 1024 + c) = H.u;
    }
}

// ---------------- MFMA projection GEMM, 128x128 tile, BK=64, 2-phase prefetch ----------------
__global__ __launch_bounds__(256) void mfma_proj(
    const ushort* __restrict__ A2, const ushort* __restrict__ B2,
    const float* __restrict__ bq, const float* __restrict__ bk_, const float* __restrict__ bv,
    float* __restrict__ q, float* __restrict__ k, float* __restrict__ v)
{
    const int p = blockIdx.z;
    const float* bias = (p == 0) ? bq : ((p == 1) ? bk_ : bv);
    float* out = (p == 0) ? q : ((p == 1) ? k : v);
    const ushort* B = B2 + (long)p * DD * KT;

    __shared__ __attribute__((aligned(16))) ushort As[128 * 64];
    __shared__ __attribute__((aligned(16))) ushort Bs[128 * 64];

    const int tid = threadIdx.x;
    const int lane = tid & 63, w = tid >> 6;
    const int wr = w >> 1, wc = w & 1;
    const int m0 = blockIdx.x * 128, n0 = blockIdx.y * 128;

    const int t8 = tid >> 3;                 // 0..31: staging row within 32-row chunk
    const int kke = (tid & 7) * 8;           // element offset of 16B piece
    const int kkb = kke * 2;                 // byte offset
    const int ln15 = lane & 15;
    const int kb0 = (lane >> 4) * 16;        // byte offset of k-block
    const int rsw = (lane & 7) << 4;         // read-side swizzle

    f32x4 acc[4][4] = {};
    uint4 aS[4], bS[4];

    // prologue: load k0 = 0
    #pragma unroll
    for (int c = 0; c < 4; ++c) {
        int row = c * 32 + t8;
        aS[c] = *(const uint4*)(A2 + (long)(m0 + row) * KT + kke);
        bS[c] = *(const uint4*)(B  + (long)(n0 + row) * KT + kke);
    }

    for (int k0 = 0; k0 < KT; k0 += 64) {
        __syncthreads();    // previous iteration's LDS reads done
        #pragma unroll
        for (int c = 0; c < 4; ++c) {
            int row = c * 32 + t8;
            int dst = row * 128 + (kkb ^ ((row & 7) << 4));
            *(uint4*)((char*)As + dst) = aS[c];
            *(uint4*)((char*)Bs + dst) = bS[c];
        }
        __syncthreads();    // tile visible
        if (k0 + 64 < KT) { // prefetch next tile; latency hides under MFMA below
            #pragma unroll
            for (int c = 0; c < 4; ++c) {
                int row = c * 32 + t8;
                aS[c] = *(const uint4*)(A2 + (long)(m0 + row) * KT + (k0 + 64) + kke);
                bS[c] = *(const uint4*)(B  + (long)(n0 + row) * KT + (k0 + 64) + kke);
            }
        }
        #pragma unroll
        for (int ks = 0; ks < 2; ++ks) {
            const int kb = (ks * 64 + kb0) ^ rsw;
            bf16x8 af[4], bfr[4];
            #pragma unroll
            for (int i = 0; i < 4; ++i)
                af[i] = *(const bf16x8*)((const char*)As + (wr * 64 + i * 16 + ln15) * 128 + kb);
            #pragma unroll
            for (int j = 0; j < 4; ++j)
                bfr[j] = *(const bf16x8*)((const char*)Bs + (wc * 64 + j * 16 + ln15) * 128 + kb);
            #pragma unroll
            for (int i = 0; i < 4; ++i)
                #pragma unroll
                for (int j = 0; j < 4; ++j)
                    acc[i][j] = __builtin_amdgcn_mfma_f32_16x16x32_bf16(af[i], bfr[j], acc[i][j], 0, 0, 0);
        }
    }

    // epilogue: D col=lane&15, row=(lane>>4)*4+r
    float bb[4];
    #pragma unroll
    for (int j = 0; j < 4; ++j) bb[j] = bias[n0 + wc * 64 + j * 16 + ln15];
    #pragma unroll
    for (int i = 0; i < 4; ++i) {
        #pragma unroll
        for (int j = 0; j < 4; ++j) {
            const int n = n0 + wc * 64 + j * 16 + ln15;
            #pragma unroll
            for (int r = 0; r < 4; ++r) {
                const int m = m0 + wr * 64 + i * 16 + (lane >> 4) * 4 + r;
                out[(((long)(m >> 11) * HH + (n >> 6)) * LL + (m & (LL - 1))) * DK + (n & 63)] =
                    acc[i][j][r] + bb[j];
            }
        }
    }
}

// ---------------- sampled QK^T and M = max - sum/L ----------------
__global__ __launch_bounds__(256) void qk_sample_M(
    const float* __restrict__ q, const float* __restrict__ k,
    const int* __restrict__ idxs, float* __restrict__ M)
{
    const int bh = blockIdx.x >> 5;
    const int l0 = (blockIdx.x & 31) * 64;
    __shared__ float qs[64][DK];
    __shared__ float qk[64][SK];
    const int tid = threadIdx.x;

    const float* qbase = q + ((long)bh * LL + l0) * DK;
    for (int f = tid; f < 64 * DK / 4; f += 256) {
        int row = f >> 4, c4 = (f & 15) * 4;
        *(float4*)&qs[row][c4] = *(const float4*)&qbase[row * DK + c4];
    }
    __syncthreads();

    const float* kbase = k + (long)bh * LL * DK;
    for (int p = tid; p < 64 * SK; p += 256) {
        int lloc = p / SK, s = p - lloc * SK;
        int idx = idxs[(l0 + lloc) * SK + s];
        const float* kr = kbase + (long)idx * DK;
        float acc = 0.f;
        #pragma unroll
        for (int c = 0; c < DK; c += 4) {
            float4 kv = *(const float4*)&kr[c];
            acc += qs[lloc][c] * kv.x + qs[lloc][c + 1] * kv.y
                 + qs[lloc][c + 2] * kv.z + qs[lloc][c + 3] * kv.w;
        }
        qk[lloc][s] = acc;
    }
    __syncthreads();

    if (tid < 64) {
        float mx = -INFINITY, sm = 0.f;
        #pragma unroll
        for (int s = 0; s < SK; ++s) { float t = qk[tid][s]; mx = fmaxf(mx, t); sm += t; }
        M[(long)bh * LL + l0 + tid] = mx - sm / (float)LL;
    }
}

// ---------------- top-40 per (b,h): single wave, in-register ----------------
__global__ __launch_bounds__(64) void topk_M(const float* __restrict__ M, int* __restrict__ Mtop)
{
    const int bh = blockIdx.x;
    const int lane = threadIdx.x;
    float vals[32];
    #pragma unroll
    for (int r = 0; r < 32; ++r) vals[r] = M[(long)bh * LL + r * 64 + lane];

    for (int it = 0; it < UU; ++it) {
        float lm = vals[0];
        #pragma unroll
        for (int r = 1; r < 32; ++r) lm = fmaxf(lm, vals[r]);
        float wm = lm;
        #pragma unroll
        for (int s = 1; s < 64; s <<= 1) wm = fmaxf(wm, __shfl_xor(wm, s, 64));
        unsigned long long mask = __ballot(lm == wm);
        int first = (int)__ffsll(mask) - 1;
        if (lane == first) {
            #pragma unroll
            for (int r = 0; r < 32; ++r) {
                if (vals[r] == wm) { Mtop[bh * UU + it] = r * 64 + lane; vals[r] = -INFINITY; break; }
            }
        }
    }
}

// ---------------- fused scores + softmax for 5 selected rows per block ----------------
__global__ __launch_bounds__(256) void scoresm(
    const float* __restrict__ q, const float* __restrict__ k,
    const int* __restrict__ Mtop, float* __restrict__ attns)
{
    const int bh = blockIdx.x >> 3;      // 8 blocks per bh, 5 u each
    const int g  = blockIdx.x & 7;
    const int tid = threadIdx.x;
    const int lane = tid & 63, wave = tid >> 6;
    __shared__ int usel[5];
    __shared__ float qs[5][DK];
    __shared__ float sc[5][LL];          // 40 KB
    __shared__ float red[5][4];

    if (tid < 5) usel[tid] = Mtop[bh * UU + g * 5 + tid];
    __syncthreads();
    if (tid < 80) {
        int u = tid >> 4, c4 = (tid & 15) * 4;
        *(float4*)&qs[u][c4] = *(const float4*)&q[((long)bh * LL + usel[u]) * DK + c4];
    }
    __syncthreads();

    // scores: thread owns rows tid + r*256
    const float* kb = k + (long)bh * LL * DK;
    float a[8][5] = {};
    #pragma unroll
    for (int c = 0; c < DK; c += 4) {
        float4 qv[5];
        #pragma unroll
        for (int u = 0; u < 5; ++u) qv[u] = *(const float4*)&qs[u][c];
        #pragma unroll
        for (int r = 0; r < 8; ++r) {
            float4 kv = *(const float4*)&kb[(long)(tid + r * 256) * DK + c];
            #pragma unroll
            for (int u = 0; u < 5; ++u)
                a[r][u] += qv[u].x * kv.x + qv[u].y * kv.y + qv[u].z * kv.z + qv[u].w * kv.w;
        }
    }
    const float scale = 0.125f;
    #pragma unroll
    for (int r = 0; r < 8; ++r)
        #pragma unroll
        for (int u = 0; u < 5; ++u)
            sc[u][tid + r * 256] = a[r][u] * scale;
    __syncthreads();

    // softmax: thread owns contiguous l = tid*8 .. +7, values in regs
    float xv[5][8];
    #pragma unroll
    for (int u = 0; u < 5; ++u) {
        float4 t0 = *(const float4*)&sc[u][tid * 8];
        float4 t1 = *(const float4*)&sc[u][tid * 8 + 4];
        xv[u][0] = t0.x; xv[u][1] = t0.y; xv[u][2] = t0.z; xv[u][3] = t0.w;
        xv[u][4] = t1.x; xv[u][5] = t1.y; xv[u][6] = t1.z; xv[u][7] = t1.w;
    }
    float mloc[5];
    #pragma unroll
    for (int u = 0; u < 5; ++u) {
        float m = xv[u][0];
        #pragma unroll
        for (int i = 1; i < 8; ++i) m = fmaxf(m, xv[u][i]);
        #pragma unroll
        for (int s = 1; s < 64; s <<= 1) m = fmaxf(m, __shfl_xor(m, s, 64));
        if (lane == 0) red[u][wave] = m;
        mloc[u] = m;
    }
    __syncthreads();
    #pragma unroll
    for (int u = 0; u < 5; ++u)
        mloc[u] = fmaxf(fmaxf(red[u][0], red[u][1]), fmaxf(red[u][2], red[u][3]));
    __syncthreads();
    float sloc[5];
    #pragma unroll
    for (int u = 0; u < 5; ++u) {
        float s = 0.f;
        #pragma unroll
        for (int i = 0; i < 8; ++i) { xv[u][i] = expf(xv[u][i] - mloc[u]); s += xv[u][i]; }
        #pragma unroll
        for (int st = 1; st < 64; st <<= 1) s += __shfl_xor(s, st, 64);
        if (lane == 0) red[u][wave] = s;
        sloc[u] = s;
    }
    __syncthreads();
    #pragma unroll
    for (int u = 0; u < 5; ++u) {
        float inv = 1.0f / (red[u][0] + red[u][1] + red[u][2] + red[u][3]);
        float* row = attns + ((long)bh * LL + usel[u]) * LL;
        float4 o0, o1;
        o0.x = xv[u][0] * inv; o0.y = xv[u][1] * inv; o0.z = xv[u][2] * inv; o0.w = xv[u][3] * inv;
        o1.x = xv[u][4] * inv; o1.y = xv[u][5] * inv; o1.z = xv[u][6] * inv; o1.w = xv[u][7] * inv;
        *(float4*)&row[tid * 8] = o0;
        *(float4*)&row[tid * 8 + 4] = o1;
    }
}

// ---------------- upd partial: per (bh, l-chunk) 40x64 partial GEMM ----------------
__global__ __launch_bounds__(256) void upd_partial(
    const float* __restrict__ v, const int* __restrict__ Mtop,
    const float* __restrict__ attns, float* __restrict__ partial)
{
    const int bh = blockIdx.x >> 4;
    const int ch = blockIdx.x & 15;
    const int l0 = ch * 128;
    __shared__ int mt[UU];
    __shared__ float pl[UU][128];
    __shared__ float vl[128][DK];
    const int tid = threadIdx.x;

    if (tid < UU) mt[tid] = Mtop[bh * UU + tid];
    __syncthreads();
    for (int f = tid; f < UU * 32; f += 256) {
        int u = f >> 5, l4 = (f & 31) * 4;
        *(float4*)&pl[u][l4] = *(const float4*)&attns[((long)bh * LL + mt[u]) * LL + l0 + l4];
    }
    for (int f = tid; f < 128 * 16; f += 256) {
        int l = f >> 4, c4 = (f & 15) * 4;
        *(float4*)&vl[l][c4] = *(const float4*)&v[((long)bh * LL + l0 + l) * DK + c4];
    }
    __syncthreads();

    const int d = tid & 63, uu = tid >> 6;
    float acc[10] = {};
    for (int l = 0; l < 128; ++l) {
        float vv = vl[l][d];
        #pragma unroll
        for (int i = 0; i < 10; ++i) acc[i] += pl[uu * 10 + i][l] * vv;
    }
    #pragma unroll
    for (int i = 0; i < 10; ++i) {
        int u = uu * 10 + i;
        partial[((long)blockIdx.x * UU + u) * DK + d] = acc[i];
    }
}

// ---------------- cumsum of v: 2-phase (carry inline in p3) ----------------
__global__ __launch_bounds__(256) void cumsum_p1(const float* __restrict__ v, float* __restrict__ sums)
{
    const int bh = blockIdx.x;
    const int d = threadIdx.x & 63, sc_ = threadIdx.x >> 6;
    const int chunk = blockIdx.y * 4 + sc_;
    const float* vb = v + ((long)bh * LL + chunk * 32) * DK + d;
    float s = 0.f;
    #pragma unroll
    for (int r = 0; r < 32; ++r) s += vb[r * DK];
    sums[((long)bh * 64 + chunk) * DK + d] = s;
}

__global__ __launch_bounds__(256) void cumsum_p3(
    const float* __restrict__ v, const float* __restrict__ sums, float* __restrict__ ctx)
{
    const int bh = blockIdx.x;
    const int d = threadIdx.x & 63, sc_ = threadIdx.x >> 6;
    const int chunk = blockIdx.y * 4 + sc_;
    float carry = 0.f;
    for (int c = 0; c < chunk; ++c) carry += sums[((long)bh * 64 + c) * DK + d];
    const float* vb = v + ((long)bh * LL + chunk * 32) * DK + d;
    float* cb = ctx + ((long)bh * LL + chunk * 32) * DK + d;
    float run = carry;
    #pragma unroll
    for (int r = 0; r < 32; ++r) { run += vb[r * DK]; cb[r * DK] = run; }
}

// ---------------- reduce partials and scatter into ctx ----------------
__global__ __launch_bounds__(64) void reduce_scatter(
    const int* __restrict__ Mtop, const float* __restrict__ partial, float* __restrict__ ctx)
{
    const int g = blockIdx.x;           // BH*UU
    const int bh = g / UU, u = g - bh * UU;
    const int lsel = Mtop[g];
    const int d = threadIdx.x;
    float s = 0.f;
    #pragma unroll
    for (int ch = 0; ch < 16; ++ch)
        s += partial[(((long)(bh * 16 + ch)) * UU + u) * DK + d];
    ctx[((long)bh * LL + lsel) * DK + d] = s;
}

extern "C" void kernel_launch(void* const* d_in, const int* in_sizes, int n_in,
                              void* d_out, int out_size, void* d_ws, size_t ws_size,
                              hipStream_t stream) {
    const float* x  = (const float*)d_in[0];
    const float* Wq = (const float*)d_in[1];
    const float* bq = (const float*)d_in[2];
    const float* Wk = (const float*)d_in[3];
    const float* bk = (const float*)d_in[4];
    const float* Wv = (const float*)d_in[5];
    const float* bv = (const float*)d_in[6];
    const int* idxs = (const int*)d_in[7];

    float* ctx   = (float*)d_out;                            // B*H*L*DK
    float* attns = (float*)d_out + (long)BB * HH * LL * DK;  // B*H*L*L (268 MB)

    char* w = (char*)d_ws;
    float* q       = (float*)w; w += (size_t)BB * HH * LL * DK * 4;
    float* k       = (float*)w; w += (size_t)BB * HH * LL * DK * 4;
    float* v       = (float*)w; w += (size_t)BB * HH * LL * DK * 4;
    float* M       = (float*)w; w += (size_t)BB * HH * LL * 4;
    int*   Mtop    = (int*)w;   w += (size_t)BB * HH * UU * 4;
    float* partial = (float*)w; w += (size_t)BH * 16 * UU * DK * 4;
    float* sums    = (float*)w; w += (size_t)BH * 64 * DK * 4;

    // pack scratch in the tail of the attns region (consumed before fill_attns)
    ushort* A2 = (ushort*)(attns + (long)50 * 1024 * 1024);
    ushort* B2 = (ushort*)(attns + (long)56 * 1024 * 1024);

    // 1) split-bf16 packing (x and W)
    pack_all<<<1408, 256, 0, stream>>>(x, Wq, Wk, Wv, A2, B2);

    // 2) MFMA projection GEMM (q,k,v), 2-phase prefetch
    dim3 g1(4096 / 128, DD / 128, 3);   // 32 x 4 x 3 = 384 blocks
    mfma_proj<<<g1, 256, 0, stream>>>(A2, B2, bq, bk, bv, q, k, v);

    // 3) fill attns with 1/L (overwrites pack scratch)
    fill_attns<<<4096, 256, 0, stream>>>(attns, (long)BB * HH * LL * LL / 4);

    // 4) sampled QK^T -> M
    qk_sample_M<<<BH * (LL / 64), 256, 0, stream>>>(q, k, idxs, M);

    // 5) top-40 indices per (b,h)
    topk_M<<<BH, 64, 0, stream>>>(M, Mtop);

    // 6) fused scores + softmax into attns rows
    scoresm<<<BH * 8, 256, 0, stream>>>(q, k, Mtop, attns);

    // 7) upd = attn @ v, split over 16 l-chunks
    upd_partial<<<BH * 16, 256, 0, stream>>>(v, Mtop, attns, partial);

    // 8) context = cumsum(v): chunk sums, then scan+emit with inline carry
    dim3 gc(BH, 16);
    cumsum_p1<<<gc, 256, 0, stream>>>(v, sums);
    cumsum_p3<<<gc, 256, 0, stream>>>(v, sums, ctx);

    // 9) reduce partials, scatter into ctx
    reduce_scatter<<<BH * UU, 64, 0, stream>>>(Mtop, partial, ctx);
}

// Round 5
// 304.761 us; speedup vs baseline: 1.1453x; 1.1453x over previous
//
#include <hip/hip_runtime.h>
#include <math.h>

#define BB 2
#define LL 2048
#define DD 512
#define HH 8
#define DK 64
#define SK 40   // sample_k
#define UU 40   // top-k u
#define BH (BB*HH)   // 16

// =============== K1: proj_gemm (blocks 0..383) || fill_attns (blocks 384..2431) ===============
__global__ __launch_bounds__(256) void k1_proj_fill(
    const float* __restrict__ x,
    const float* __restrict__ Wq, const float* __restrict__ bq,
    const float* __restrict__ Wk, const float* __restrict__ bk,
    const float* __restrict__ Wv, const float* __restrict__ bv,
    float* __restrict__ q, float* __restrict__ k, float* __restrict__ v,
    float* __restrict__ attns)
{
    const int tid = threadIdx.x;

    if (blockIdx.x >= 384) {
        // ---- fill job: 2048 blocks x 8192 float4 ----
        const float c = 1.0f / (float)LL;
        const float4 val = make_float4(c, c, c, c);
        float4* p = (float4*)attns + (long)(blockIdx.x - 384) * 8192 + tid;
        #pragma unroll
        for (int i = 0; i < 32; ++i) p[i * 256] = val;
        return;
    }

    // ---- proj job: 384 blocks = 3 proj x 4 col-tiles x 32 row-tiles ----
    const int pb = blockIdx.x;
    const int pz = pb >> 7;            // 0..2
    const int rem = pb & 127;
    const int by = rem >> 5;           // 0..3
    const int bx = rem & 31;           // 0..31

    const float* W; const float* bias; float* out;
    if (pz == 0)      { W = Wq; bias = bq; out = q; }
    else if (pz == 1) { W = Wk; bias = bk; out = k; }
    else              { W = Wv; bias = bv; out = v; }

    __shared__ float As[16][132];   // [k][row]
    __shared__ float Bs[16][132];   // [k][col]
    const int n0 = bx * 128;        // rows over B*L = 4096
    const int o0 = by * 128;        // cols over D = 512
    const int tx = tid & 15, ty = tid >> 4;

    float acc[8][8] = {};

    for (int k0 = 0; k0 < DD; k0 += 16) {
        #pragma unroll
        for (int f = tid; f < 512; f += 256) {
            int row = f >> 2, c4 = (f & 3) * 4;
            const float4 xv = *(const float4*)&x[(long)(n0 + row) * DD + k0 + c4];
            As[c4 + 0][row] = xv.x; As[c4 + 1][row] = xv.y;
            As[c4 + 2][row] = xv.z; As[c4 + 3][row] = xv.w;
        }
        #pragma unroll
        for (int f = tid; f < 512; f += 256) {
            int o = f >> 2, c4 = (f & 3) * 4;
            const float4 wv = *(const float4*)&W[(long)(o0 + o) * DD + k0 + c4];
            Bs[c4 + 0][o] = wv.x; Bs[c4 + 1][o] = wv.y;
            Bs[c4 + 2][o] = wv.z; Bs[c4 + 3][o] = wv.w;
        }
        __syncthreads();
        #pragma unroll
        for (int kk = 0; kk < 16; ++kk) {
            float a[8], b[8];
            *(float4*)&a[0] = *(const float4*)&As[kk][ty * 8];
            *(float4*)&a[4] = *(const float4*)&As[kk][ty * 8 + 4];
            *(float4*)&b[0] = *(const float4*)&Bs[kk][tx * 8];
            *(float4*)&b[4] = *(const float4*)&Bs[kk][tx * 8 + 4];
            #pragma unroll
            for (int i = 0; i < 8; ++i)
                #pragma unroll
                for (int j = 0; j < 8; ++j) acc[i][j] += a[i] * b[j];
        }
        __syncthreads();
    }

    const int col0 = o0 + tx * 8;
    const int h = col0 >> 6, d0 = col0 & 63;
    float br[8];
    #pragma unroll
    for (int j = 0; j < 8; ++j) br[j] = bias[col0 + j];
    #pragma unroll
    for (int i = 0; i < 8; ++i) {
        int n = n0 + ty * 8 + i;
        int b_ = n >> 11, l = n & (LL - 1);
        float* orow = out + (((long)b_ * HH + h) * LL + l) * DK + d0;
        float4 o0v, o1v;
        o0v.x = acc[i][0] + br[0]; o0v.y = acc[i][1] + br[1];
        o0v.z = acc[i][2] + br[2]; o0v.w = acc[i][3] + br[3];
        o1v.x = acc[i][4] + br[4]; o1v.y = acc[i][5] + br[5];
        o1v.z = acc[i][6] + br[6]; o1v.w = acc[i][7] + br[7];
        *(float4*)&orow[0] = o0v;
        *(float4*)&orow[4] = o1v;
    }
}

// =============== K2: qk_sample_M (blocks 0..511) || cumsum_p1 (blocks 512..767) ===============
__global__ __launch_bounds__(256) void k2_qk_cumsum1(
    const float* __restrict__ q, const float* __restrict__ k, const float* __restrict__ v,
    const int* __restrict__ idxs, float* __restrict__ M, float* __restrict__ sums)
{
    const int tid = threadIdx.x;

    if (blockIdx.x >= 512) {
        // ---- cumsum phase 1: per-(bh, chunk) column sums of v ----
        const int b = blockIdx.x - 512;
        const int bh = b >> 4;
        const int d = tid & 63, sc_ = tid >> 6;
        const int chunk = (b & 15) * 4 + sc_;
        const float* vb = v + ((long)bh * LL + chunk * 32) * DK + d;
        float s = 0.f;
        #pragma unroll
        for (int r = 0; r < 32; ++r) s += vb[r * DK];
        sums[((long)bh * 64 + chunk) * DK + d] = s;
        return;
    }

    const int bh = blockIdx.x >> 5;
    const int l0 = (blockIdx.x & 31) * 64;
    __shared__ float qs[64][DK];
    __shared__ float qk[64][SK];

    const float* qbase = q + ((long)bh * LL + l0) * DK;
    for (int f = tid; f < 64 * DK / 4; f += 256) {
        int row = f >> 4, c4 = (f & 15) * 4;
        *(float4*)&qs[row][c4] = *(const float4*)&qbase[row * DK + c4];
    }
    __syncthreads();

    const float* kbase = k + (long)bh * LL * DK;
    for (int p = tid; p < 64 * SK; p += 256) {
        int lloc = p / SK, s = p - lloc * SK;
        int idx = idxs[(l0 + lloc) * SK + s];
        const float* kr = kbase + (long)idx * DK;
        float acc = 0.f;
        #pragma unroll
        for (int c = 0; c < DK; c += 4) {
            float4 kv = *(const float4*)&kr[c];
            acc += qs[lloc][c] * kv.x + qs[lloc][c + 1] * kv.y
                 + qs[lloc][c + 2] * kv.z + qs[lloc][c + 3] * kv.w;
        }
        qk[lloc][s] = acc;
    }
    __syncthreads();

    if (tid < 64) {
        float mx = -INFINITY, sm = 0.f;
        #pragma unroll
        for (int s = 0; s < SK; ++s) { float t = qk[tid][s]; mx = fmaxf(mx, t); sm += t; }
        M[(long)bh * LL + l0 + tid] = mx - sm / (float)LL;
    }
}

// =============== K3: topk (blocks 0..15, wave 0) || cumsum_p3 (blocks 16..271) ===============
__global__ __launch_bounds__(256) void k3_topk_cumsum3(
    const float* __restrict__ M, int* __restrict__ Mtop,
    const float* __restrict__ v, const float* __restrict__ sums, float* __restrict__ ctx)
{
    const int tid = threadIdx.x;

    if (blockIdx.x >= 16) {
        // ---- cumsum phase 3: emit prefix sums with inline carry ----
        const int b = blockIdx.x - 16;
        const int bh = b >> 4;
        const int d = tid & 63, sc_ = tid >> 6;
        const int chunk = (b & 15) * 4 + sc_;
        float carry = 0.f;
        for (int c = 0; c < chunk; ++c) carry += sums[((long)bh * 64 + c) * DK + d];
        const float* vb = v + ((long)bh * LL + chunk * 32) * DK + d;
        float* cb = ctx + ((long)bh * LL + chunk * 32) * DK + d;
        float run = carry;
        #pragma unroll
        for (int r = 0; r < 32; ++r) { run += vb[r * DK]; cb[r * DK] = run; }
        return;
    }

    if (tid >= 64) return;
    // ---- top-40: single wave, in-register ----
    const int bh = blockIdx.x;
    const int lane = tid;
    float vals[32];
    #pragma unroll
    for (int r = 0; r < 32; ++r) vals[r] = M[(long)bh * LL + r * 64 + lane];

    for (int it = 0; it < UU; ++it) {
        float lm = vals[0];
        #pragma unroll
        for (int r = 1; r < 32; ++r) lm = fmaxf(lm, vals[r]);
        float wm = lm;
        #pragma unroll
        for (int s = 1; s < 64; s <<= 1) wm = fmaxf(wm, __shfl_xor(wm, s, 64));
        unsigned long long mask = __ballot(lm == wm);
        int first = (int)__ffsll(mask) - 1;
        if (lane == first) {
            #pragma unroll
            for (int r = 0; r < 32; ++r) {
                if (vals[r] == wm) { Mtop[bh * UU + it] = r * 64 + lane; vals[r] = -INFINITY; break; }
            }
        }
    }
}

// =============== K4: fused scores + softmax for 5 selected rows per block ===============
__global__ __launch_bounds__(256) void scoresm(
    const float* __restrict__ q, const float* __restrict__ k,
    const int* __restrict__ Mtop, float* __restrict__ attns)
{
    const int bh = blockIdx.x >> 3;
    const int g  = blockIdx.x & 7;
    const int tid = threadIdx.x;
    const int lane = tid & 63, wave = tid >> 6;
    __shared__ int usel[5];
    __shared__ float qs[5][DK];
    __shared__ float sc[5][LL];
    __shared__ float red[5][4];

    if (tid < 5) usel[tid] = Mtop[bh * UU + g * 5 + tid];
    __syncthreads();
    if (tid < 80) {
        int u = tid >> 4, c4 = (tid & 15) * 4;
        *(float4*)&qs[u][c4] = *(const float4*)&q[((long)bh * LL + usel[u]) * DK + c4];
    }
    __syncthreads();

    const float* kb = k + (long)bh * LL * DK;
    float a[8][5] = {};
    #pragma unroll
    for (int c = 0; c < DK; c += 4) {
        float4 qv[5];
        #pragma unroll
        for (int u = 0; u < 5; ++u) qv[u] = *(const float4*)&qs[u][c];
        #pragma unroll
        for (int r = 0; r < 8; ++r) {
            float4 kv = *(const float4*)&kb[(long)(tid + r * 256) * DK + c];
            #pragma unroll
            for (int u = 0; u < 5; ++u)
                a[r][u] += qv[u].x * kv.x + qv[u].y * kv.y + qv[u].z * kv.z + qv[u].w * kv.w;
        }
    }
    const float scale = 0.125f;
    #pragma unroll
    for (int r = 0; r < 8; ++r)
        #pragma unroll
        for (int u = 0; u < 5; ++u)
            sc[u][tid + r * 256] = a[r][u] * scale;
    __syncthreads();

    float xv[5][8];
    #pragma unroll
    for (int u = 0; u < 5; ++u) {
        float4 t0 = *(const float4*)&sc[u][tid * 8];
        float4 t1 = *(const float4*)&sc[u][tid * 8 + 4];
        xv[u][0] = t0.x; xv[u][1] = t0.y; xv[u][2] = t0.z; xv[u][3] = t0.w;
        xv[u][4] = t1.x; xv[u][5] = t1.y; xv[u][6] = t1.z; xv[u][7] = t1.w;
    }
    float mloc[5];
    #pragma unroll
    for (int u = 0; u < 5; ++u) {
        float m = xv[u][0];
        #pragma unroll
        for (int i = 1; i < 8; ++i) m = fmaxf(m, xv[u][i]);
        #pragma unroll
        for (int s = 1; s < 64; s <<= 1) m = fmaxf(m, __shfl_xor(m, s, 64));
        if (lane == 0) red[u][wave] = m;
        mloc[u] = m;
    }
    __syncthreads();
    #pragma unroll
    for (int u = 0; u < 5; ++u)
        mloc[u] = fmaxf(fmaxf(red[u][0], red[u][1]), fmaxf(red[u][2], red[u][3]));
    __syncthreads();
    #pragma unroll
    for (int u = 0; u < 5; ++u) {
        float s = 0.f;
        #pragma unroll
        for (int i = 0; i < 8; ++i) { xv[u][i] = expf(xv[u][i] - mloc[u]); s += xv[u][i]; }
        #pragma unroll
        for (int st = 1; st < 64; st <<= 1) s += __shfl_xor(s, st, 64);
        if (lane == 0) red[u][wave] = s;
    }
    __syncthreads();
    #pragma unroll
    for (int u = 0; u < 5; ++u) {
        float inv = 1.0f / (red[u][0] + red[u][1] + red[u][2] + red[u][3]);
        float* row = attns + ((long)bh * LL + usel[u]) * LL;
        float4 o0, o1;
        o0.x = xv[u][0] * inv; o0.y = xv[u][1] * inv; o0.z = xv[u][2] * inv; o0.w = xv[u][3] * inv;
        o1.x = xv[u][4] * inv; o1.y = xv[u][5] * inv; o1.z = xv[u][6] * inv; o1.w = xv[u][7] * inv;
        *(float4*)&row[tid * 8] = o0;
        *(float4*)&row[tid * 8 + 4] = o1;
    }
}

// =============== K5: upd partial GEMM per (bh, l-chunk) ===============
__global__ __launch_bounds__(256) void upd_partial(
    const float* __restrict__ v, const int* __restrict__ Mtop,
    const float* __restrict__ attns, float* __restrict__ partial)
{
    const int bh = blockIdx.x >> 4;
    const int ch = blockIdx.x & 15;
    const int l0 = ch * 128;
    __shared__ int mt[UU];
    __shared__ float pl[UU][128];
    __shared__ float vl[128][DK];
    const int tid = threadIdx.x;

    if (tid < UU) mt[tid] = Mtop[bh * UU + tid];
    __syncthreads();
    for (int f = tid; f < UU * 32; f += 256) {
        int u = f >> 5, l4 = (f & 31) * 4;
        *(float4*)&pl[u][l4] = *(const float4*)&attns[((long)bh * LL + mt[u]) * LL + l0 + l4];
    }
    for (int f = tid; f < 128 * 16; f += 256) {
        int l = f >> 4, c4 = (f & 15) * 4;
        *(float4*)&vl[l][c4] = *(const float4*)&v[((long)bh * LL + l0 + l) * DK + c4];
    }
    __syncthreads();

    const int d = tid & 63, uu = tid >> 6;
    float acc[10] = {};
    for (int l = 0; l < 128; ++l) {
        float vv = vl[l][d];
        #pragma unroll
        for (int i = 0; i < 10; ++i) acc[i] += pl[uu * 10 + i][l] * vv;
    }
    #pragma unroll
    for (int i = 0; i < 10; ++i) {
        int u = uu * 10 + i;
        partial[((long)blockIdx.x * UU + u) * DK + d] = acc[i];
    }
}

// =============== K6: reduce partials and scatter, 4 (bh,u) pairs per block ===============
__global__ __launch_bounds__(256) void reduce_scatter4(
    const int* __restrict__ Mtop, const float* __restrict__ partial, float* __restrict__ ctx)
{
    const int g = blockIdx.x * 4 + (threadIdx.x >> 6);   // 0..639
    const int bh = g / UU, u = g - bh * UU;
    const int lsel = Mtop[g];
    const int d = threadIdx.x & 63;
    float s = 0.f;
    #pragma unroll
    for (int ch = 0; ch < 16; ++ch)
        s += partial[(((long)(bh * 16 + ch)) * UU + u) * DK + d];
    ctx[((long)bh * LL + lsel) * DK + d] = s;
}

extern "C" void kernel_launch(void* const* d_in, const int* in_sizes, int n_in,
                              void* d_out, int out_size, void* d_ws, size_t ws_size,
                              hipStream_t stream) {
    const float* x  = (const float*)d_in[0];
    const float* Wq = (const float*)d_in[1];
    const float* bq = (const float*)d_in[2];
    const float* Wk = (const float*)d_in[3];
    const float* bk = (const float*)d_in[4];
    const float* Wv = (const float*)d_in[5];
    const float* bv = (const float*)d_in[6];
    const int* idxs = (const int*)d_in[7];

    float* ctx   = (float*)d_out;                            // B*H*L*DK
    float* attns = (float*)d_out + (long)BB * HH * LL * DK;  // B*H*L*L

    char* w = (char*)d_ws;
    float* q       = (float*)w; w += (size_t)BB * HH * LL * DK * 4;
    float* k       = (float*)w; w += (size_t)BB * HH * LL * DK * 4;
    float* v       = (float*)w; w += (size_t)BB * HH * LL * DK * 4;
    float* M       = (float*)w; w += (size_t)BB * HH * LL * 4;
    int*   Mtop    = (int*)w;   w += (size_t)BB * HH * UU * 4;
    float* partial = (float*)w; w += (size_t)BH * 16 * UU * DK * 4;
    float* sums    = (float*)w; w += (size_t)BH * 64 * DK * 4;

    // K1: projections (384 blocks) || fill attns (2048 blocks)
    k1_proj_fill<<<384 + 2048, 256, 0, stream>>>(x, Wq, bq, Wk, bk, Wv, bv, q, k, v, attns);

    // K2: sampled QK^T -> M (512) || cumsum chunk sums (256)
    k2_qk_cumsum1<<<512 + 256, 256, 0, stream>>>(q, k, v, idxs, M, sums);

    // K3: top-40 (16) || cumsum emit (256)
    k3_topk_cumsum3<<<16 + 256, 256, 0, stream>>>(M, Mtop, v, sums, ctx);

    // K4: fused scores + softmax into attns rows
    scoresm<<<BH * 8, 256, 0, stream>>>(q, k, Mtop, attns);

    // K5: upd = attn @ v, split over 16 l-chunks
    upd_partial<<<BH * 16, 256, 0, stream>>>(v, Mtop, attns, partial);

    // K6: reduce partials, scatter into ctx
    reduce_scatter4<<<160, 256, 0, stream>>>(Mtop, partial, ctx);
}

// Round 6
// 279.574 us; speedup vs baseline: 1.2485x; 1.0901x over previous
//
#include <hip/hip_runtime.h>
#include <math.h>

#define BB 2
#define LL 2048
#define DD 512
#define HH 8
#define DK 64
#define SK 40   // sample_k
#define UU 40   // top-k u
#define BH (BB*HH)   // 16

typedef __attribute__((ext_vector_type(8))) __bf16 bf16x8;
typedef __attribute__((ext_vector_type(4))) float f32x4;

__device__ inline ushort f2bf_rn(float f) {
    unsigned u = __float_as_uint(f);
    unsigned r = (u + 0x7fffu + ((u >> 16) & 1u)) >> 16;
    return (ushort)r;
}
__device__ inline float bf2f(ushort h) { return __uint_as_float(((unsigned)h) << 16); }

__device__ __forceinline__ void gload16(const ushort* g, void* l) {
    __builtin_amdgcn_global_load_lds(
        (const __attribute__((address_space(1))) unsigned int*)g,
        (__attribute__((address_space(3))) unsigned int*)l,
        16, 0, 0);
}

// =============== K0: pack x -> Ah/Al, W -> Bh/Bl (split-bf16) ===============
__global__ __launch_bounds__(256) void pack_split(
    const float* __restrict__ x,
    const float* __restrict__ Wq, const float* __restrict__ Wk, const float* __restrict__ Wv,
    ushort* __restrict__ Ah, ushort* __restrict__ Al,
    ushort* __restrict__ Bh, ushort* __restrict__ Bl)
{
    const int bid = blockIdx.x;
    const float* src; ushort* dh; ushort* dl;
    if (bid < 1024) {
        const int g = bid * 256 + threadIdx.x;       // 0..262143
        const int r = g >> 6, c = (g & 63) * 8;
        src = x + (long)r * DD + c;
        dh = Ah + (long)r * DD + c;
        dl = Al + (long)r * DD + c;
    } else {
        const int wb = bid - 1024;
        const int p = wb >> 7;
        const float* W = (p == 0) ? Wq : ((p == 1) ? Wk : Wv);
        const int rem = (wb & 127) * 256 + threadIdx.x;  // 0..32767
        const int r = rem >> 6, c = (rem & 63) * 8;
        src = W + (long)r * DD + c;
        dh = Bh + ((long)p * DD + r) * DD + c;
        dl = Bl + ((long)p * DD + r) * DD + c;
    }
    const float4 f0 = *(const float4*)&src[0];
    const float4 f1 = *(const float4*)&src[4];
    float f[8] = {f0.x, f0.y, f0.z, f0.w, f1.x, f1.y, f1.z, f1.w};
    union { ushort s[8]; uint4 u; } H, L;
    #pragma unroll
    for (int i = 0; i < 8; ++i) {
        H.s[i] = f2bf_rn(f[i]);
        L.s[i] = f2bf_rn(f[i] - bf2f(H.s[i]));
    }
    *(uint4*)dh = H.u;
    *(uint4*)dl = L.u;
}

// =============== K1: MFMA proj (blocks 0..383) || fill attns (384..2431) ===============
// proj: C = [xh|xh|xl] @ [Wh|Wl|Wh]^T + b, m97 structure: gload_lds 16B, linear LDS,
// 128x128 tile, BK=64, 2-barrier loop. K = 3 segments of 512.
__global__ __launch_bounds__(256) void k1_proj_fill(
    const ushort* __restrict__ Ah, const ushort* __restrict__ Al,
    const ushort* __restrict__ Bh, const ushort* __restrict__ Bl,
    const float* __restrict__ bq, const float* __restrict__ bk_, const float* __restrict__ bv,
    float* __restrict__ q, float* __restrict__ k, float* __restrict__ v,
    float* __restrict__ attns)
{
    const int tid = threadIdx.x;

    if (blockIdx.x >= 384) {
        // ---- fill job ----
        const float c = 1.0f / (float)LL;
        const float4 val = make_float4(c, c, c, c);
        float4* p = (float4*)attns + (long)(blockIdx.x - 384) * 8192 + tid;
        #pragma unroll
        for (int i = 0; i < 32; ++i) p[i * 256] = val;
        return;
    }

    const int pz = blockIdx.x >> 7;          // proj 0..2
    const int rem = blockIdx.x & 127;
    const int o0 = (rem >> 5) * 128;         // n tile over D=512
    const int m0 = (rem & 31) * 128;         // m tile over B*L=4096
    const float* bias = (pz == 0) ? bq : ((pz == 1) ? bk_ : bv);
    float* out = (pz == 0) ? q : ((pz == 1) ? k : v);

    const ushort* Bp = Bh + (long)pz * DD * DD;
    const ushort* Blp = Bl + (long)pz * DD * DD;
    const ushort* segA[3] = {Ah, Ah, Al};
    const ushort* segB[3] = {Bp, Blp, Bp};

    __shared__ __attribute__((aligned(16))) ushort As[128 * 64];
    __shared__ __attribute__((aligned(16))) ushort Bs[128 * 64];

    const int lane = tid & 63, w = tid >> 6;
    const int wr = w >> 1, wc = w & 1;
    const int ln15 = lane & 15;
    const int l3 = lane >> 3, l7 = (lane & 7) * 8;   // gload lane mapping

    f32x4 acc[4][4] = {};

    for (int t = 0; t < 24; ++t) {
        const ushort* Aseg = segA[t >> 3];
        const ushort* Bseg = segB[t >> 3];
        const int k0 = (t & 7) * 64;
        __syncthreads();    // prior iteration's LDS reads complete
        #pragma unroll
        for (int c = 0; c < 8; ++c) {
            const int j = w * 8 + c;    // 0..31, wave-uniform
            if (j < 16) {
                gload16(Aseg + (long)(m0 + j * 8 + l3) * DD + k0 + l7,
                        (char*)As + j * 1024);
            } else {
                const int j2 = j - 16;
                gload16(Bseg + (long)(o0 + j2 * 8 + l3) * DD + k0 + l7,
                        (char*)Bs + j2 * 1024);
            }
        }
        __syncthreads();    // drains vmcnt(0): staged tile visible
        #pragma unroll
        for (int ks = 0; ks < 2; ++ks) {
            const int kb = ks * 64 + (lane >> 4) * 16;   // byte offset in 128B row
            bf16x8 bfr[4];
            #pragma unroll
            for (int jj = 0; jj < 4; ++jj)
                bfr[jj] = *(const bf16x8*)((const char*)Bs + (wc * 64 + jj * 16 + ln15) * 128 + kb);
            #pragma unroll
            for (int i = 0; i < 4; ++i) {
                bf16x8 af = *(const bf16x8*)((const char*)As + (wr * 64 + i * 16 + ln15) * 128 + kb);
                #pragma unroll
                for (int jj = 0; jj < 4; ++jj)
                    acc[i][jj] = __builtin_amdgcn_mfma_f32_16x16x32_bf16(af, bfr[jj], acc[i][jj], 0, 0, 0);
            }
        }
    }

    // epilogue: D col=lane&15, row=(lane>>4)*4+r  (R3/R4-verified)
    const int n_base = o0 + wc * 64;
    float bb[4];
    #pragma unroll
    for (int jj = 0; jj < 4; ++jj) bb[jj] = bias[n_base + jj * 16 + ln15];
    #pragma unroll
    for (int i = 0; i < 4; ++i) {
        #pragma unroll
        for (int jj = 0; jj < 4; ++jj) {
            const int n = n_base + jj * 16 + ln15;
            #pragma unroll
            for (int r = 0; r < 4; ++r) {
                const int m = m0 + wr * 64 + i * 16 + (lane >> 4) * 4 + r;
                out[(((long)(m >> 11) * HH + (n >> 6)) * LL + (m & (LL - 1))) * DK + (n & 63)] =
                    acc[i][jj][r] + bb[jj];
            }
        }
    }
}

// =============== K2: qk_sample reg-q (blocks 0..127) || cumsum_p1 (128..383) ===============
__global__ __launch_bounds__(256) void k2_qk_cumsum1(
    const float* __restrict__ q, const float* __restrict__ k, const float* __restrict__ v,
    const int* __restrict__ idxs, float* __restrict__ M, float* __restrict__ sums)
{
    const int tid = threadIdx.x;

    if (blockIdx.x >= 128) {
        const int b = blockIdx.x - 128;
        const int bh = b >> 4;
        const int d = tid & 63, sc_ = tid >> 6;
        const int chunk = (b & 15) * 4 + sc_;
        const float* vb = v + ((long)bh * LL + chunk * 32) * DK + d;
        float s = 0.f;
        #pragma unroll
        for (int r = 0; r < 32; ++r) s += vb[r * DK];
        sums[((long)bh * 64 + chunk) * DK + d] = s;
        return;
    }

    const int g = blockIdx.x * 256 + tid;
    const int bh = g >> 11, l = g & (LL - 1);
    const float* qr = q + ((long)bh * LL + l) * DK;
    float4 qv[16];
    #pragma unroll
    for (int i = 0; i < 16; ++i) qv[i] = *(const float4*)&qr[i * 4];

    const int* ir = idxs + (long)l * SK;
    const float* kb = k + (long)bh * LL * DK;
    float mx = -INFINITY, sm = 0.f;
    for (int s = 0; s < SK; ++s) {
        const float* kr = kb + (long)ir[s] * DK;
        float acc = 0.f;
        #pragma unroll
        for (int i = 0; i < 16; ++i) {
            float4 kv = *(const float4*)&kr[i * 4];
            acc += qv[i].x * kv.x + qv[i].y * kv.y + qv[i].z * kv.z + qv[i].w * kv.w;
        }
        mx = fmaxf(mx, acc); sm += acc;
    }
    M[(long)bh * LL + l] = mx - sm * (1.0f / (float)LL);
}

// =============== K3: topk (blocks 0..15) || cumsum_p3 (16..271) ===============
__global__ __launch_bounds__(256) void k3_topk_cumsum3(
    const float* __restrict__ M, int* __restrict__ Mtop,
    const float* __restrict__ v, const float* __restrict__ sums, float* __restrict__ ctx)
{
    const int tid = threadIdx.x;

    if (blockIdx.x >= 16) {
        const int b = blockIdx.x - 16;
        const int bh = b >> 4;
        const int d = tid & 63, sc_ = tid >> 6;
        const int chunk = (b & 15) * 4 + sc_;
        float carry = 0.f;
        for (int c = 0; c < chunk; ++c) carry += sums[((long)bh * 64 + c) * DK + d];
        const float* vb = v + ((long)bh * LL + chunk * 32) * DK + d;
        float* cb = ctx + ((long)bh * LL + chunk * 32) * DK + d;
        float run = carry;
        #pragma unroll
        for (int r = 0; r < 32; ++r) { run += vb[r * DK]; cb[r * DK] = run; }
        return;
    }

    if (tid >= 64) return;
    const int bh = blockIdx.x;
    const int lane = tid;
    float vals[32];
    #pragma unroll
    for (int r = 0; r < 32; ++r) vals[r] = M[(long)bh * LL + r * 64 + lane];

    for (int it = 0; it < UU; ++it) {
        float lm = vals[0];
        #pragma unroll
        for (int r = 1; r < 32; ++r) lm = fmaxf(lm, vals[r]);
        float wm = lm;
        #pragma unroll
        for (int s = 1; s < 64; s <<= 1) wm = fmaxf(wm, __shfl_xor(wm, s, 64));
        unsigned long long mask = __ballot(lm == wm);
        int first = (int)__ffsll(mask) - 1;
        if (lane == first) {
            #pragma unroll
            for (int r = 0; r < 32; ++r) {
                if (vals[r] == wm) { Mtop[bh * UU + it] = r * 64 + lane; vals[r] = -INFINITY; break; }
            }
        }
    }
}

// =============== K4: scores + softmax + upd + scatter (5 rows per block) ===============
__global__ __launch_bounds__(256) void k4_scores_upd(
    const float* __restrict__ q, const float* __restrict__ k, const float* __restrict__ v,
    const int* __restrict__ Mtop, float* __restrict__ attns, float* __restrict__ ctx)
{
    const int bh = blockIdx.x >> 3;
    const int g  = blockIdx.x & 7;
    const int tid = threadIdx.x;
    const int lane = tid & 63, wave = tid >> 6;
    __shared__ int usel[5];
    __shared__ float qs[5][DK];
    __shared__ float sc[5][LL];          // 40 KB
    __shared__ float red[5][4];
    __shared__ float red2[4][5][DK];     // 5 KB

    if (tid < 5) usel[tid] = Mtop[bh * UU + g * 5 + tid];
    __syncthreads();
    if (tid < 80) {
        int u = tid >> 4, c4 = (tid & 15) * 4;
        *(float4*)&qs[u][c4] = *(const float4*)&q[((long)bh * LL + usel[u]) * DK + c4];
    }
    __syncthreads();

    // scores: thread owns k-rows tid + r*256
    const float* kb = k + (long)bh * LL * DK;
    float a[8][5] = {};
    #pragma unroll
    for (int c = 0; c < DK; c += 4) {
        float4 qv[5];
        #pragma unroll
        for (int u = 0; u < 5; ++u) qv[u] = *(const float4*)&qs[u][c];
        #pragma unroll
        for (int r = 0; r < 8; ++r) {
            float4 kv = *(const float4*)&kb[(long)(tid + r * 256) * DK + c];
            #pragma unroll
            for (int u = 0; u < 5; ++u)
                a[r][u] += qv[u].x * kv.x + qv[u].y * kv.y + qv[u].z * kv.z + qv[u].w * kv.w;
        }
    }
    const float scale = 0.125f;
    #pragma unroll
    for (int r = 0; r < 8; ++r)
        #pragma unroll
        for (int u = 0; u < 5; ++u)
            sc[u][tid + r * 256] = a[r][u] * scale;
    __syncthreads();

    // softmax in regs over l = tid*8..+7
    float xv[5][8];
    #pragma unroll
    for (int u = 0; u < 5; ++u) {
        float4 t0 = *(const float4*)&sc[u][tid * 8];
        float4 t1 = *(const float4*)&sc[u][tid * 8 + 4];
        xv[u][0] = t0.x; xv[u][1] = t0.y; xv[u][2] = t0.z; xv[u][3] = t0.w;
        xv[u][4] = t1.x; xv[u][5] = t1.y; xv[u][6] = t1.z; xv[u][7] = t1.w;
    }
    float mloc[5];
    #pragma unroll
    for (int u = 0; u < 5; ++u) {
        float m = xv[u][0];
        #pragma unroll
        for (int i = 1; i < 8; ++i) m = fmaxf(m, xv[u][i]);
        #pragma unroll
        for (int s = 1; s < 64; s <<= 1) m = fmaxf(m, __shfl_xor(m, s, 64));
        if (lane == 0) red[u][wave] = m;
        mloc[u] = m;
    }
    __syncthreads();
    #pragma unroll
    for (int u = 0; u < 5; ++u)
        mloc[u] = fmaxf(fmaxf(red[u][0], red[u][1]), fmaxf(red[u][2], red[u][3]));
    __syncthreads();
    #pragma unroll
    for (int u = 0; u < 5; ++u) {
        float s = 0.f;
        #pragma unroll
        for (int i = 0; i < 8; ++i) { xv[u][i] = expf(xv[u][i] - mloc[u]); s += xv[u][i]; }
        #pragma unroll
        for (int st = 1; st < 64; st <<= 1) s += __shfl_xor(s, st, 64);
        if (lane == 0) red[u][wave] = s;
    }
    __syncthreads();
    #pragma unroll
    for (int u = 0; u < 5; ++u) {
        float inv = 1.0f / (red[u][0] + red[u][1] + red[u][2] + red[u][3]);
        float* row = attns + ((long)bh * LL + usel[u]) * LL;
        float4 o0, o1;
        o0.x = xv[u][0] * inv; o0.y = xv[u][1] * inv; o0.z = xv[u][2] * inv; o0.w = xv[u][3] * inv;
        o1.x = xv[u][4] * inv; o1.y = xv[u][5] * inv; o1.z = xv[u][6] * inv; o1.w = xv[u][7] * inv;
        *(float4*)&row[tid * 8] = o0;
        *(float4*)&row[tid * 8 + 4] = o1;
        *(float4*)&sc[u][tid * 8] = o0;       // normalized probs back to LDS for upd
        *(float4*)&sc[u][tid * 8 + 4] = o1;
    }
    __syncthreads();

    // upd: remap to (d, part); upd[u][d] = sum_l sc[u][l] * v[l][d]
    const int d = tid & 63, part = tid >> 6;
    const float* vb = v + (long)bh * LL * DK + d;
    float ua[5] = {};
    for (int l0 = part * 512; l0 < part * 512 + 512; l0 += 4) {
        float vv0 = vb[(long)(l0 + 0) * DK];
        float vv1 = vb[(long)(l0 + 1) * DK];
        float vv2 = vb[(long)(l0 + 2) * DK];
        float vv3 = vb[(long)(l0 + 3) * DK];
        #pragma unroll
        for (int u = 0; u < 5; ++u) {
            float4 pv = *(const float4*)&sc[u][l0];
            ua[u] += pv.x * vv0 + pv.y * vv1 + pv.z * vv2 + pv.w * vv3;
        }
    }
    #pragma unroll
    for (int u = 0; u < 5; ++u) red2[part][u][d] = ua[u];
    __syncthreads();
    if (part == 0) {
        #pragma unroll
        for (int u = 0; u < 5; ++u) {
            float s = red2[0][u][d] + red2[1][u][d] + red2[2][u][d] + red2[3][u][d];
            ctx[((long)bh * LL + usel[u]) * DK + d] = s;
        }
    }
}

extern "C" void kernel_launch(void* const* d_in, const int* in_sizes, int n_in,
                              void* d_out, int out_size, void* d_ws, size_t ws_size,
                              hipStream_t stream) {
    const float* x  = (const float*)d_in[0];
    const float* Wq = (const float*)d_in[1];
    const float* bq = (const float*)d_in[2];
    const float* Wk = (const float*)d_in[3];
    const float* bk = (const float*)d_in[4];
    const float* Wv = (const float*)d_in[5];
    const float* bv = (const float*)d_in[6];
    const int* idxs = (const int*)d_in[7];

    float* ctx   = (float*)d_out;                            // B*H*L*DK (8 MB)
    float* attns = (float*)d_out + (long)BB * HH * LL * DK;  // B*H*L*L (268 MB)

    char* w = (char*)d_ws;
    float* q    = (float*)w; w += (size_t)BB * HH * LL * DK * 4;
    float* k    = (float*)w; w += (size_t)BB * HH * LL * DK * 4;
    float* v    = (float*)w; w += (size_t)BB * HH * LL * DK * 4;
    float* M    = (float*)w; w += (size_t)BB * HH * LL * 4;
    int*  Mtop  = (int*)w;   w += (size_t)BB * HH * UU * 4;
    float* sums = (float*)w; w += (size_t)BH * 64 * DK * 4;
    ushort* Bh  = (ushort*)w; w += (size_t)3 * DD * DD * 2;
    ushort* Bl  = (ushort*)w; w += (size_t)3 * DD * DD * 2;

    // Ah/Al live in the ctx output region (dead until K3 writes it)
    ushort* Ah = (ushort*)ctx;                  // 4 MB
    ushort* Al = Ah + (size_t)4096 * DD;        // 4 MB

    // K0: split-bf16 packing
    pack_split<<<1408, 256, 0, stream>>>(x, Wq, Wk, Wv, Ah, Al, Bh, Bl);

    // K1: MFMA projections (384 blocks) || fill attns (2048 blocks)
    k1_proj_fill<<<384 + 2048, 256, 0, stream>>>(Ah, Al, Bh, Bl, bq, bk, bv, q, k, v, attns);

    // K2: sampled QK^T -> M (128) || cumsum chunk sums (256)
    k2_qk_cumsum1<<<128 + 256, 256, 0, stream>>>(q, k, v, idxs, M, sums);

    // K3: top-40 (16) || cumsum emit (256)
    k3_topk_cumsum3<<<16 + 256, 256, 0, stream>>>(M, Mtop, v, sums, ctx);

    // K4: scores + softmax + upd + scatter
    k4_scores_upd<<<BH * 8, 256, 0, stream>>>(q, k, v, Mtop, attns, ctx);
}